// Round 3
// baseline (64.392 us; speedup 1.0000x reference)
//
#include <hip/hip_runtime.h>
#include <stdint.h>

// Problem shapes (fixed by setup_inputs)
#define BB 8
#define NN 4096
#define FF 2048
#define EE 128

typedef __attribute__((ext_vector_type(8))) short short8;
typedef __attribute__((ext_vector_type(4))) float floatx4;

__device__ __forceinline__ unsigned short f2bf(float x) {
    union { float f; uint32_t u; } v; v.f = x;
    uint32_t u = v.u;
    return (unsigned short)((u + 0x7FFFu + ((u >> 16) & 1u)) >> 16);
}

__device__ __forceinline__ float wred_sum(float v) {
#pragma unroll
    for (int o = 32; o; o >>= 1) v += __shfl_xor(v, o, 64);
    return v;
}

#define NFB (BB * FF / 4)   // 4096 blocks for fact prep (4 waves each)
#define NEB (BB * NN / 4)   // 8192 blocks for entity prep

// ---------------------------------------------------------------------------
// Fused prep: fact branch computes C_sp/C_po + bf16 swizzled fact2/fact3;
// entity branch computes ||ent||^2 + bf16 linear ent rows.
// ---------------------------------------------------------------------------
__global__ __launch_bounds__(256) void prep_all(
    const float* __restrict__ rel, const float* __restrict__ arg1,
    const float* __restrict__ arg2, const float* __restrict__ f1,
    const float* __restrict__ f2, const float* __restrict__ f3,
    const float* __restrict__ ent, const int* __restrict__ nbf,
    unsigned short* __restrict__ f2b, unsigned short* __restrict__ f3b,
    unsigned short* __restrict__ entb,
    float* __restrict__ Csp, float* __restrict__ Cpo, float* __restrict__ enorm)
{
    int lane = threadIdx.x & 63;
    if (blockIdx.x < NFB) {
        int gid = blockIdx.x * 4 + (threadIdx.x >> 6);   // over B*F
        int b = gid >> 11;
        int f = gid & (FF - 1);

        const float2* rp  = (const float2*)(rel  + (size_t)b * EE);
        const float2* a1p = (const float2*)(arg1 + (size_t)b * EE);
        const float2* a2p = (const float2*)(arg2 + (size_t)b * EE);
        const float2* p1  = (const float2*)(f1 + (size_t)gid * EE);
        const float2* p2  = (const float2*)(f2 + (size_t)gid * EE);
        const float2* p3  = (const float2*)(f3 + (size_t)gid * EE);

        float2 vr = rp[lane], va1 = a1p[lane], va2 = a2p[lane];
        float2 v1 = p1[lane], v2 = p2[lane], v3 = p3[lane];

        float dx, dy;
        dx = vr.x - v1.x;  dy = vr.y - v1.y;  float dr  = dx*dx + dy*dy;
        dx = va1.x - v2.x; dy = va1.y - v2.y; float da1 = dx*dx + dy*dy;
        dx = va2.x - v3.x; dy = va2.y - v3.y; float da2 = dx*dx + dy*dy;
        float s2 = v2.x*v2.x + v2.y*v2.y;
        float s3 = v3.x*v3.x + v3.y*v3.y;

        // bf16 swizzled store: 16B slot j -> j ^ (f&7)
        int slot = lane >> 2;
        int swz  = slot ^ (f & 7);
        size_t dbyte = (size_t)gid * 256 + (size_t)(swz << 4) + ((lane & 3) << 2);
        uint32_t pk2 = (uint32_t)f2bf(v2.x) | ((uint32_t)f2bf(v2.y) << 16);
        uint32_t pk3 = (uint32_t)f2bf(v3.x) | ((uint32_t)f2bf(v3.y) << 16);
        *(uint32_t*)((char*)f2b + dbyte) = pk2;
        *(uint32_t*)((char*)f3b + dbyte) = pk3;

        dr = wred_sum(dr); da1 = wred_sum(da1); da2 = wred_sum(da2);
        s2 = wred_sum(s2); s3 = wred_sum(s3);

        if (lane == 0) {
            bool fv = f < nbf[b];
            Csp[gid] = fv ? (dr + da1 + s3) : 1e30f;
            Cpo[gid] = fv ? (dr + da2 + s2) : 1e30f;
        }
    } else {
        int gid = (blockIdx.x - NFB) * 4 + (threadIdx.x >> 6);   // over B*N
        const float2* p = (const float2*)(ent + (size_t)gid * EE);
        float2 v = p[lane];
        uint32_t pk = (uint32_t)f2bf(v.x) | ((uint32_t)f2bf(v.y) << 16);
        *(uint32_t*)((char*)entb + (size_t)gid * 256 + (lane << 2)) = pk;
        float nrm = wred_sum(v.x*v.x + v.y*v.y);
        if (lane == 0) enorm[gid] = nrm;
    }
}

// ---------------------------------------------------------------------------
// Main fused GEMM-min kernel.
// Grid 512 = b(8, low bits: XCD affinity) x ntile(16) x fsplit(4).
// Block 256 threads (4 waves); wave owns 64 entity rows (I=4 strips of 16)
// -> 256-row N-tile. 2 blocks/CU (128KB LDS) = 8 waves/CU = 2 waves/SIMD:
// cross-block overlap hides barrier drains (independent barrier domains).
// F-quarter = 512 facts, tiles of 128; fact3/fact2 tiles alternate as a
// natural double buffer: stage next tile before computing current.
// B-read:MFMA ratio = 1:4. Writes partial min-distances to pm.
// ---------------------------------------------------------------------------
__device__ __forceinline__ void stage_tile(const char* src, char* dst, int w, int lane) {
    const char* g = src + w * 8192 + lane * 16;
    char* l = dst + w * 8192 + lane * 16;
#pragma unroll
    for (int it = 0; it < 8; ++it)
        __builtin_amdgcn_global_load_lds(
            (const __attribute__((address_space(1))) void*)(g + it * 1024),
            (__attribute__((address_space(3))) void*)(l + it * 1024), 16, 0, 0);
}

__device__ __forceinline__ void compute_tile(
    const char* buf, const float* __restrict__ cvec,
    const short8 (&a)[4][4], int l15, int kgrp, int lane, float (&rm)[4][4])
{
#pragma unroll
    for (int fj = 0; fj < 8; ++fj) {
        int row = fj * 16 + l15;
        const char* rp = buf + row * 256;
        int sw = lane & 7;
        short8 bf[4];
#pragma unroll
        for (int kk = 0; kk < 4; ++kk)
            bf[kk] = *(const short8*)(rp + (((kk * 4 + kgrp) ^ sw) << 4));
        floatx4 acc[4];
#pragma unroll
        for (int i = 0; i < 4; ++i) acc[i] = floatx4{0.f, 0.f, 0.f, 0.f};
#pragma unroll
        for (int kk = 0; kk < 4; ++kk)
#pragma unroll
            for (int i = 0; i < 4; ++i)
                acc[i] = __builtin_amdgcn_mfma_f32_16x16x32_bf16(
                    a[i][kk], bf[kk], acc[i], 0, 0, 0);
        float c = cvec[fj * 16 + l15];
#pragma unroll
        for (int i = 0; i < 4; ++i) {
            float v0 = fmaf(-2.f, acc[i][0], c);
            float v1 = fmaf(-2.f, acc[i][1], c);
            float v2 = fmaf(-2.f, acc[i][2], c);
            float v3 = fmaf(-2.f, acc[i][3], c);
            rm[i][0] = fminf(rm[i][0], v0);
            rm[i][1] = fminf(rm[i][1], v1);
            rm[i][2] = fminf(rm[i][2], v2);
            rm[i][3] = fminf(rm[i][3], v3);
        }
    }
}

__global__ __launch_bounds__(256, 2) void kb_main(
    const unsigned short* __restrict__ entb,
    const unsigned short* __restrict__ f2b,
    const unsigned short* __restrict__ f3b,
    const float* __restrict__ Csp, const float* __restrict__ Cpo,
    float* __restrict__ pm)
{
    __shared__ char b3[32768];
    __shared__ char b2[32768];

    int bid = blockIdx.x;
    int b  = bid & 7;
    int nt = (bid >> 3) & 15;
    int fs = bid >> 7;
    int nbase = nt * 256;
    int fbase = fs * 512;

    int tid = threadIdx.x, w = tid >> 6, lane = tid & 63;
    int l15 = lane & 15, kgrp = lane >> 4;

    // A-frags: ent rows nbase + w*64 + i*16 + l15, all K
    short8 a[4][4];
    {
        const unsigned short* pe = entb + ((size_t)b * NN + nbase + w * 64) * EE;
#pragma unroll
        for (int i = 0; i < 4; ++i) {
            const unsigned short* pr = pe + (size_t)(i * 16 + l15) * EE + kgrp * 8;
#pragma unroll
            for (int kk = 0; kk < 4; ++kk)
                a[i][kk] = *(const short8*)(pr + kk * 32);
        }
    }

    float rm3[4][4], rm2[4][4];
#pragma unroll
    for (int i = 0; i < 4; ++i)
#pragma unroll
        for (int r = 0; r < 4; ++r) { rm3[i][r] = 3.0e38f; rm2[i][r] = 3.0e38f; }

    const char* s3 = (const char*)f3b + ((size_t)b * FF + fbase) * 256;
    const char* s2 = (const char*)f2b + ((size_t)b * FF + fbase) * 256;
    const float* c3 = Csp + b * FF + fbase;
    const float* c2 = Cpo + b * FF + fbase;

    stage_tile(s3, b3, w, lane);
    __syncthreads();

    for (int ft = 0; ft < 4; ++ft) {
        stage_tile(s2 + (size_t)ft * 32768, b2, w, lane);      // in flight
        compute_tile(b3, c3 + ft * 128, a, l15, kgrp, lane, rm3);
        __syncthreads();                                        // drains, b2 ready
        if (ft < 3) stage_tile(s3 + (size_t)(ft + 1) * 32768, b3, w, lane);
        compute_tile(b2, c2 + ft * 128, a, l15, kgrp, lane, rm2);
        __syncthreads();                                        // b3 ready
    }

    // lane-group min-reduce, write partial min-distances
    float* p0 = pm + (((size_t)fs * 2 + 0) * BB + b) * NN + nbase + w * 64;
    float* p1 = pm + (((size_t)fs * 2 + 1) * BB + b) * NN + nbase + w * 64;
#pragma unroll
    for (int i = 0; i < 4; ++i)
#pragma unroll
        for (int r = 0; r < 4; ++r) {
            float vs = rm3[i][r], vp = rm2[i][r];
#pragma unroll
            for (int o = 1; o < 16; o <<= 1) {
                vs = fminf(vs, __shfl_xor(vs, o, 64));
                vp = fminf(vp, __shfl_xor(vp, o, 64));
            }
            if (l15 == 0) {
                int row = i * 16 + kgrp * 4 + r;
                p0[row] = vs;
                p1[row] = vp;
            }
        }
}

// ---------------------------------------------------------------------------
// Combine: min over the 4 F-split partials, add ||ent||^2, exp, entity mask.
// ---------------------------------------------------------------------------
__global__ __launch_bounds__(512) void combine(
    const float* __restrict__ pm, const float* __restrict__ enorm,
    const int* __restrict__ nbe, float* __restrict__ out)
{
    int idx = blockIdx.x * 512 + threadIdx.x;   // over 2*B*N
    int br  = idx >> 15;
    int rem = idx & 32767;
    int b   = rem >> 12;
    int n   = rem & 4095;
    float d = 3.0e38f;
#pragma unroll
    for (int fs = 0; fs < 4; ++fs)
        d = fminf(d, pm[(((size_t)fs * 2 + br) * BB + b) * NN + n]);
    bool valid = n < nbe[b];
    out[idx] = valid ? __expf(-0.5f * (d + enorm[(size_t)b * NN + n])) : 0.f;
}

// ---------------------------------------------------------------------------
// Workspace layout (bytes):
//   [0,      4MB)   fact2 bf16 (swizzled)
//   [4MB,    8MB)   fact3 bf16 (swizzled)
//   [8MB,   16MB)   ent bf16 (linear)
//   [16MB,        +64KB)   C_sp
//   [16MB+64K,    +64KB)   C_po
//   [16MB+128K,  +128KB)   ent_norm
//   [16MB+256K,    +1MB)   pm partial mins [fs*2+branch][B][N]
// ---------------------------------------------------------------------------
extern "C" void kernel_launch(void* const* d_in, const int* in_sizes, int n_in,
                              void* d_out, int out_size, void* d_ws, size_t ws_size,
                              hipStream_t stream) {
    const float* rel  = (const float*)d_in[0];
    const float* arg1 = (const float*)d_in[1];
    const float* arg2 = (const float*)d_in[2];
    const float* f1   = (const float*)d_in[3];
    const float* f2   = (const float*)d_in[4];
    const float* f3   = (const float*)d_in[5];
    const float* ent  = (const float*)d_in[6];
    const int*   nbf  = (const int*)d_in[7];
    const int*   nbe  = (const int*)d_in[8];

    char* ws = (char*)d_ws;
    unsigned short* f2b  = (unsigned short*)(ws);
    unsigned short* f3b  = (unsigned short*)(ws + (4u << 20));
    unsigned short* entb = (unsigned short*)(ws + (8u << 20));
    float* Csp   = (float*)(ws + (16u << 20));
    float* Cpo   = (float*)(ws + (16u << 20) + 65536);
    float* enorm = (float*)(ws + (16u << 20) + 131072);
    float* pm    = (float*)(ws + (16u << 20) + 262144);
    float* out = (float*)d_out;

    hipLaunchKernelGGL(prep_all, dim3(NFB + NEB), dim3(256), 0, stream,
                       rel, arg1, arg2, f1, f2, f3, ent, nbf,
                       f2b, f3b, entb, Csp, Cpo, enorm);
    hipLaunchKernelGGL(kb_main, dim3(512), dim3(256), 0, stream,
                       entb, f2b, f3b, Csp, Cpo, pm);
    hipLaunchKernelGGL(combine, dim3(128), dim3(512), 0, stream,
                       pm, enorm, nbe, out);
}

// Round 4
// 52.359 us; speedup vs baseline: 1.2298x; 1.2298x over previous
//
#include <hip/hip_runtime.h>
#include <stdint.h>

// Problem shapes (fixed by setup_inputs)
#define BB 8
#define NN 4096
#define FF 2048
#define EE 128

typedef __attribute__((ext_vector_type(8))) short short8;
typedef __attribute__((ext_vector_type(4))) float floatx4;

__device__ __forceinline__ unsigned short f2bf(float x) {
    union { float f; uint32_t u; } v; v.f = x;
    uint32_t u = v.u;
    return (unsigned short)((u + 0x7FFFu + ((u >> 16) & 1u)) >> 16);
}

__device__ __forceinline__ float wred_sum(float v) {
#pragma unroll
    for (int o = 32; o; o >>= 1) v += __shfl_xor(v, o, 64);
    return v;
}

#define NFB (BB * FF / 4)   // 4096 blocks for fact prep (4 waves each)
#define NEB (BB * NN / 4)   // 8192 blocks for entity prep

// ---------------------------------------------------------------------------
// Fused prep. Fact branch: C_sp/C_po + fact2/fact3 as bf16 scaled by -2,
// stored MFMA-fragment-tiled: [b][ftile=f/16][kslot=k/8][row=f%16][8 bf16]
// so the main kernel's B-frag loads are wave-contiguous 1KB.
// Entity branch: ||ent||^2 + ent bf16 in the same tiled layout (unscaled).
// ---------------------------------------------------------------------------
__global__ __launch_bounds__(256) void prep_all(
    const float* __restrict__ rel, const float* __restrict__ arg1,
    const float* __restrict__ arg2, const float* __restrict__ f1,
    const float* __restrict__ f2, const float* __restrict__ f3,
    const float* __restrict__ ent, const int* __restrict__ nbf,
    char* __restrict__ f2t, char* __restrict__ f3t, char* __restrict__ entt,
    float* __restrict__ Csp, float* __restrict__ Cpo, float* __restrict__ enorm)
{
    int lane = threadIdx.x & 63;
    if (blockIdx.x < NFB) {
        int gid = blockIdx.x * 4 + (threadIdx.x >> 6);   // over B*F
        int b = gid >> 11;
        int f = gid & (FF - 1);

        const float2* rp  = (const float2*)(rel  + (size_t)b * EE);
        const float2* a1p = (const float2*)(arg1 + (size_t)b * EE);
        const float2* a2p = (const float2*)(arg2 + (size_t)b * EE);
        const float2* p1  = (const float2*)(f1 + (size_t)gid * EE);
        const float2* p2  = (const float2*)(f2 + (size_t)gid * EE);
        const float2* p3  = (const float2*)(f3 + (size_t)gid * EE);

        float2 vr = rp[lane], va1 = a1p[lane], va2 = a2p[lane];
        float2 v1 = p1[lane], v2 = p2[lane], v3 = p3[lane];

        float dx, dy;
        dx = vr.x - v1.x;  dy = vr.y - v1.y;  float dr  = dx*dx + dy*dy;
        dx = va1.x - v2.x; dy = va1.y - v2.y; float da1 = dx*dx + dy*dy;
        dx = va2.x - v3.x; dy = va2.y - v3.y; float da2 = dx*dx + dy*dy;
        float s2 = v2.x*v2.x + v2.y*v2.y;
        float s3 = v3.x*v3.x + v3.y*v3.y;

        // tiled store of -2*fact (exact pow2 scaling in bf16)
        // lane covers k = {2*lane, 2*lane+1}; kslot = lane>>2
        size_t base = ((size_t)b << 19) + (size_t)(f >> 4) * 4096 +
                      ((size_t)(lane >> 2) << 8) + ((f & 15) << 4) + ((lane & 3) << 2);
        uint32_t pk2 = (uint32_t)f2bf(-2.f * v2.x) | ((uint32_t)f2bf(-2.f * v2.y) << 16);
        uint32_t pk3 = (uint32_t)f2bf(-2.f * v3.x) | ((uint32_t)f2bf(-2.f * v3.y) << 16);
        *(uint32_t*)(f2t + base) = pk2;
        *(uint32_t*)(f3t + base) = pk3;

        dr = wred_sum(dr); da1 = wred_sum(da1); da2 = wred_sum(da2);
        s2 = wred_sum(s2); s3 = wred_sum(s3);

        if (lane == 0) {
            bool fv = f < nbf[b];
            Csp[gid] = fv ? (dr + da1 + s3) : 1e30f;
            Cpo[gid] = fv ? (dr + da2 + s2) : 1e30f;
        }
    } else {
        int gid = (blockIdx.x - NFB) * 4 + (threadIdx.x >> 6);   // over B*N
        int b = gid >> 12;
        int n = gid & (NN - 1);
        const float2* p = (const float2*)(ent + (size_t)gid * EE);
        float2 v = p[lane];
        size_t base = ((size_t)b << 20) + (size_t)(n >> 4) * 4096 +
                      ((size_t)(lane >> 2) << 8) + ((n & 15) << 4) + ((lane & 3) << 2);
        *(uint32_t*)(entt + base) =
            (uint32_t)f2bf(v.x) | ((uint32_t)f2bf(v.y) << 16);
        float nrm = wred_sum(v.x*v.x + v.y*v.y);
        if (lane == 0) enorm[gid] = nrm;
    }
}

// ---------------------------------------------------------------------------
// Main fused GEMM-min kernel. NO LDS, NO barriers.
// 2048 independent single-wave blocks: bid = b(3 bits, XCD affinity) |
// ng(64-row group, 6 bits) | fs(2 bits). Each wave: 64 entity rows x 512
// facts x both tensors. B-frags stream from (XCD-local) L2 as wave-contiguous
// 1KB loads in MFMA layout; 2-deep register pipeline (load ft+1 under MFMA ft).
// Facts pre-scaled by -2, acc initialized from C via MFMA C-in, so the
// epilogue is min-only. Writes partial mins to pm.
// ---------------------------------------------------------------------------
__global__ __launch_bounds__(64, 2) void kb_main(
    const char* __restrict__ entt, const char* __restrict__ f3t,
    const char* __restrict__ f2t,
    const float* __restrict__ Csp, const float* __restrict__ Cpo,
    float* __restrict__ pm)
{
    int bid = blockIdx.x;
    int b  = bid & 7;
    int r  = bid >> 3;          // 0..255
    int fs = r >> 6;            // 0..3
    int ng = r & 63;            // 64-row entity group
    int lane = threadIdx.x & 63;
    int l15 = lane & 15, kgrp = lane >> 4;

    // A-frags: 64 entity rows (4 ntiles) x full K from tiled entt
    short8 a[4][4];
    {
        const char* ab = entt + ((size_t)b << 20) + ((size_t)ng << 14) + (l15 << 4);
#pragma unroll
        for (int i = 0; i < 4; ++i)
#pragma unroll
            for (int kk = 0; kk < 4; ++kk)
                a[i][kk] = *(const short8*)(ab + i * 4096 + ((kk * 4 + kgrp) << 8));
    }

    const char* p3 = f3t + ((size_t)b << 19) + (size_t)fs * (32 * 4096) +
                     (kgrp << 8) + (l15 << 4);
    const char* p2 = f2t + ((size_t)b << 19) + (size_t)fs * (32 * 4096) +
                     (kgrp << 8) + (l15 << 4);
    const float* c3 = Csp + b * FF + fs * 512 + l15;
    const float* c2 = Cpo + b * FF + fs * 512 + l15;

    float rm3[4][4], rm2[4][4];
#pragma unroll
    for (int i = 0; i < 4; ++i)
#pragma unroll
        for (int q = 0; q < 4; ++q) { rm3[i][q] = 3.0e38f; rm2[i][q] = 3.0e38f; }

    short8 bA3[4], bA2[4], bB3[4], bB2[4];

#define LOADB(d3, d2, ft) do {                                              \
    _Pragma("unroll") for (int kk = 0; kk < 4; ++kk) {                      \
        d3[kk] = *(const short8*)(p3 + (ft) * 4096 + kk * 1024);            \
        d2[kk] = *(const short8*)(p2 + (ft) * 4096 + kk * 1024);            \
    } } while (0)

#define STEP(s3v, s2v, ft) do {                                             \
    float cv3 = c3[(ft) * 16], cv2 = c2[(ft) * 16];                         \
    floatx4 acc3[4], acc2[4];                                               \
    _Pragma("unroll") for (int i = 0; i < 4; ++i) {                         \
        acc3[i] = floatx4{cv3, cv3, cv3, cv3};                              \
        acc2[i] = floatx4{cv2, cv2, cv2, cv2};                              \
    }                                                                       \
    _Pragma("unroll") for (int kk = 0; kk < 4; ++kk)                        \
        _Pragma("unroll") for (int i = 0; i < 4; ++i)                       \
            acc3[i] = __builtin_amdgcn_mfma_f32_16x16x32_bf16(              \
                a[i][kk], s3v[kk], acc3[i], 0, 0, 0);                       \
    _Pragma("unroll") for (int kk = 0; kk < 4; ++kk)                        \
        _Pragma("unroll") for (int i = 0; i < 4; ++i)                       \
            acc2[i] = __builtin_amdgcn_mfma_f32_16x16x32_bf16(              \
                a[i][kk], s2v[kk], acc2[i], 0, 0, 0);                       \
    _Pragma("unroll") for (int i = 0; i < 4; ++i)                           \
        _Pragma("unroll") for (int q = 0; q < 4; ++q) {                     \
            rm3[i][q] = fminf(rm3[i][q], acc3[i][q]);                       \
            rm2[i][q] = fminf(rm2[i][q], acc2[i][q]);                       \
        } } while (0)

    LOADB(bA3, bA2, 0);
    for (int ft = 0; ft < 32; ft += 2) {
        LOADB(bB3, bB2, ft + 1);            // prefetch odd tile
        STEP(bA3, bA2, ft);
        if (ft < 30) LOADB(bA3, bA2, ft + 2);   // prefetch next even tile
        STEP(bB3, bB2, ft + 1);
    }
#undef LOADB
#undef STEP

    // lane-group min-reduce, write partial min-distances
    float* q0 = pm + (((size_t)fs * 2 + 0) * BB + b) * NN + ng * 64;
    float* q1 = pm + (((size_t)fs * 2 + 1) * BB + b) * NN + ng * 64;
#pragma unroll
    for (int i = 0; i < 4; ++i)
#pragma unroll
        for (int q = 0; q < 4; ++q) {
            float vs = rm3[i][q], vp = rm2[i][q];
#pragma unroll
            for (int o = 1; o < 16; o <<= 1) {
                vs = fminf(vs, __shfl_xor(vs, o, 64));
                vp = fminf(vp, __shfl_xor(vp, o, 64));
            }
            if (l15 == 0) {
                int row = i * 16 + kgrp * 4 + q;
                q0[row] = vs;
                q1[row] = vp;
            }
        }
}

// ---------------------------------------------------------------------------
// Combine: min over the 4 F-split partials, add ||ent||^2, exp, entity mask.
// ---------------------------------------------------------------------------
__global__ __launch_bounds__(512) void combine(
    const float* __restrict__ pm, const float* __restrict__ enorm,
    const int* __restrict__ nbe, float* __restrict__ out)
{
    int idx = blockIdx.x * 512 + threadIdx.x;   // over 2*B*N
    int br  = idx >> 15;
    int rem = idx & 32767;
    int b   = rem >> 12;
    int n   = rem & 4095;
    float d = 3.0e38f;
#pragma unroll
    for (int fsp = 0; fsp < 4; ++fsp)
        d = fminf(d, pm[(((size_t)fsp * 2 + br) * BB + b) * NN + n]);
    bool valid = n < nbe[b];
    out[idx] = valid ? __expf(-0.5f * (d + enorm[(size_t)b * NN + n])) : 0.f;
}

// ---------------------------------------------------------------------------
// Workspace layout (bytes):
//   [0,      4MB)   fact2 bf16 * -2, MFMA-tiled
//   [4MB,    8MB)   fact3 bf16 * -2, MFMA-tiled
//   [8MB,   16MB)   ent bf16, MFMA-tiled
//   [16MB,        +64KB)   C_sp
//   [16MB+64K,    +64KB)   C_po
//   [16MB+128K,  +128KB)   ent_norm
//   [16MB+256K,    +1MB)   pm partial mins [fs*2+branch][B][N]
// ---------------------------------------------------------------------------
extern "C" void kernel_launch(void* const* d_in, const int* in_sizes, int n_in,
                              void* d_out, int out_size, void* d_ws, size_t ws_size,
                              hipStream_t stream) {
    const float* rel  = (const float*)d_in[0];
    const float* arg1 = (const float*)d_in[1];
    const float* arg2 = (const float*)d_in[2];
    const float* f1   = (const float*)d_in[3];
    const float* f2   = (const float*)d_in[4];
    const float* f3   = (const float*)d_in[5];
    const float* ent  = (const float*)d_in[6];
    const int*   nbf  = (const int*)d_in[7];
    const int*   nbe  = (const int*)d_in[8];

    char* ws = (char*)d_ws;
    char* f2t  = ws;
    char* f3t  = ws + (4u << 20);
    char* entt = ws + (8u << 20);
    float* Csp   = (float*)(ws + (16u << 20));
    float* Cpo   = (float*)(ws + (16u << 20) + 65536);
    float* enorm = (float*)(ws + (16u << 20) + 131072);
    float* pm    = (float*)(ws + (16u << 20) + 262144);
    float* out = (float*)d_out;

    hipLaunchKernelGGL(prep_all, dim3(NFB + NEB), dim3(256), 0, stream,
                       rel, arg1, arg2, f1, f2, f3, ent, nbf,
                       f2t, f3t, entt, Csp, Cpo, enorm);
    hipLaunchKernelGGL(kb_main, dim3(2048), dim3(64), 0, stream,
                       entt, f3t, f2t, Csp, Cpo, pm);
    hipLaunchKernelGGL(combine, dim3(128), dim3(512), 0, stream,
                       pm, enorm, nbe, out);
}